// Round 10
// baseline (190.458 us; speedup 1.0000x reference)
//
#include <hip/hip_runtime.h>

#define TPB 256

// ---------------------------------------------------------------------------
// partial_activation: Y[32] viewed as 16 blocks of 2, M=2, Q=2.0.
// pos[b] = #(Y[2b..2b+1] > 0); minI/maxI = FIRST argmin/argmax of pos;
// mask: *2 on max block if pos==2, *0 on min block if pos==0.
// train += relu-sum of min block (if fails) + (-negsum) of max block (if fails).
// succ += (min_succ && max_succ).
// All indexing compile-time constant (rule #20) -> Y stays in registers.
// IDENTICAL math/order to rounds 2/3/6/8/9 (all passed, absmax 0.0039) --
// do NOT reassociate: mask decisions are sign-sensitive.
// ---------------------------------------------------------------------------
__device__ __forceinline__ void partial_act(float (&Y)[32], float& t_acc, int& s_cnt)
{
    int pos[16];
#pragma unroll
    for (int b = 0; b < 16; ++b)
        pos[b] = (Y[2 * b] > 0.0f ? 1 : 0) + (Y[2 * b + 1] > 0.0f ? 1 : 0);

    int minv = pos[0], maxv = pos[0];
    int minI = 0, maxI = 0;
    float ymin0 = Y[0], ymin1 = Y[1];
    float ymax0 = Y[0], ymax1 = Y[1];
#pragma unroll
    for (int b = 1; b < 16; ++b) {
        bool lt = pos[b] < minv;   // strict < keeps FIRST argmin (jnp.argmin)
        minv  = lt ? pos[b]       : minv;
        minI  = lt ? b            : minI;
        ymin0 = lt ? Y[2 * b]     : ymin0;
        ymin1 = lt ? Y[2 * b + 1] : ymin1;
        bool gt = pos[b] > maxv;   // strict > keeps FIRST argmax (jnp.argmax)
        maxv  = gt ? pos[b]       : maxv;
        maxI  = gt ? b            : maxI;
        ymax0 = gt ? Y[2 * b]     : ymax0;
        ymax1 = gt ? Y[2 * b + 1] : ymax1;
    }
    bool min_succ = (minv == 0);
    bool max_succ = (maxv == 2);

    // train uses PRE-mask Y: y*(y>0)==max(y,0); -y*(y<0)==-min(y,0)
    float cmin = fmaxf(ymin0, 0.0f) + fmaxf(ymin1, 0.0f);
    float cmax = -(fminf(ymax0, 0.0f) + fminf(ymax1, 0.0f));
    t_acc += (min_succ ? 0.0f : cmin) + (max_succ ? 0.0f : cmax);
    s_cnt += (min_succ && max_succ) ? 1 : 0;

#pragma unroll
    for (int b = 0; b < 16; ++b) {
        bool ismax = max_succ && (b == maxI);
        bool ismin = min_succ && (b == minI);
        float mfac = ismax ? 2.0f : 1.0f;
        mfac = ismin ? 0.0f : mfac;
        Y[2 * b]     *= mfac;
        Y[2 * b + 1] *= mfac;
    }
}

// ---------------------------------------------------------------------------
// Round-10: MANY LIGHT WAVES. Findings driving this:
//  - R9: v_pk_fma_f32 is half-rate on CDNA4 (peak FP32 = scalar rate) -> no
//    win; revert to scalar fma.
//  - R6/8/9: VGPR_Count stuck at 72 with 128+ live floats => allocator parks
//    arrays in AGPRs (unified file) and pays accvgpr shuffles; effective
//    occupancy ~2.2 waves/SIMD; per-j SMEM latency (~180cy, lgkmcnt(0)-only)
//    exposed against ~40% duty -> dur latency-bound.
//  Fix: R=1 row/thread (state ~64 floats + temps ~ 100 regs) and
//  __launch_bounds__(256,4): unified cap 128/wave -> >=4 waves/SIMD. Duty
//  36%/wave x 4 waves saturates the VALU; latency hidden by TLP (the only
//  mechanism SMEM's out-of-order returns permit).
//  fma chains remain scalar, j-outer, ascending-k: bit-identical to all
//  passing rounds.
// ---------------------------------------------------------------------------
__global__ __launch_bounds__(TPB, 4) void net_main(
    const float* __restrict__ x,
    const float* __restrict__ W1, const float* __restrict__ b1,
    const float* __restrict__ W2, const float* __restrict__ b2,
    const float* __restrict__ W3, const float* __restrict__ b3,
    float* __restrict__ out,
    float* __restrict__ t_part, int* __restrict__ c_part,
    unsigned* __restrict__ counter,
    int nrows, double inv_denom)
{
    const int tid = threadIdx.x;
    const int row = blockIdx.x * TPB + tid;

    float t_acc = 0.0f;
    int   s_cnt = 0;

    if (row < nrows) {
        const float2 xv = reinterpret_cast<const float2*>(x)[row];

        // ---- layer 1 (weights uniform -> SGPR) ----
        float Y[32];
#pragma unroll
        for (int j = 0; j < 32; ++j)
            Y[j] = fmaf(xv.y, W1[2 * j + 1], fmaf(xv.x, W1[2 * j], b1[j]));

        partial_act(Y, t_acc, s_cnt);

        // ---- layer 2, j-outer: W2 row j = 32 contiguous floats in SGPRs ----
        float Z[32];
#pragma unroll
        for (int j = 0; j < 32; ++j) {
            float acc = b2[j];
#pragma unroll
            for (int k = 0; k < 32; ++k)
                acc = fmaf(Y[k], W2[32 * j + k], acc);   // ascending-k chain
            Z[j] = acc;
        }

        partial_act(Z, t_acc, s_cnt);

        // ---- layer 3 + softmax ----
        float z0 = b3[0], z1 = b3[1];
#pragma unroll
        for (int k = 0; k < 32; ++k) {
            z0 = fmaf(Z[k], W3[k], z0);
            z1 = fmaf(Z[k], W3[32 + k], z1);
        }
        float m  = fmaxf(z0, z1);
        float e0 = __expf(z0 - m);
        float e1 = __expf(z1 - m);
        float iv = 1.0f / (e0 + e1);
        float2 o;
        o.x = e0 * iv;
        o.y = e1 * iv;
        reinterpret_cast<float2*>(out)[row] = o;
    }

    // ---- block reduction: wave shuffle -> LDS -> per-block partial ----
#pragma unroll
    for (int off = 32; off; off >>= 1) {
        t_acc += __shfl_down(t_acc, off);
        s_cnt += __shfl_down(s_cnt, off);
    }
    __shared__ float ts[TPB / 64];
    __shared__ int   cs[TPB / 64];
    __shared__ bool  amLast;
    const int wid  = tid >> 6;
    const int lane = tid & 63;
    if (lane == 0) { ts[wid] = t_acc; cs[wid] = s_cnt; }
    __syncthreads();
    if (tid == 0) {
        float tt = ts[0];
        int   cc = cs[0];
#pragma unroll
        for (int w = 1; w < TPB / 64; ++w) { tt += ts[w]; cc += cs[w]; }
        t_part[blockIdx.x] = tt;
        c_part[blockIdx.x] = cc;
        __threadfence();                        // partials visible device-wide
        unsigned old = atomicAdd(counter, 1u);  // device-scope by default
        amLast = (old == gridDim.x - 1);
    }
    __syncthreads();

    // ---- last block reduces all partials (fixed order -> deterministic) ----
    if (amLast) {
        __threadfence();
        double t = 0.0;
        int    c = 0;
        const int nparts = gridDim.x;
        for (int i = tid; i < nparts; i += TPB) {
            t += (double)t_part[i];
            c += c_part[i];
        }
#pragma unroll
        for (int off = 32; off; off >>= 1) {
            t += __shfl_down(t, off);
            c += __shfl_down(c, off);
        }
        __shared__ double td[TPB / 64];
        __shared__ int    cd[TPB / 64];
        if (lane == 0) { td[wid] = t; cd[wid] = c; }
        __syncthreads();
        if (tid == 0) {
            double tt = 0.0;
            int    cc = 0;
#pragma unroll
            for (int w = 0; w < TPB / 64; ++w) { tt += td[w]; cc += cd[w]; }
            float* scal = out + (size_t)nrows * 2;
            scal[0] = (float)((double)cc * inv_denom); // succ = cnt / (2B)
            scal[1] = (float)tt;                       // train = t1 + t2
        }
    }
}

extern "C" void kernel_launch(void* const* d_in, const int* in_sizes, int n_in,
                              void* d_out, int out_size, void* d_ws, size_t ws_size,
                              hipStream_t stream)
{
    const float* x  = (const float*)d_in[0];
    const float* W1 = (const float*)d_in[1];
    const float* b1 = (const float*)d_in[2];
    const float* W2 = (const float*)d_in[3];
    const float* b2 = (const float*)d_in[4];
    const float* W3 = (const float*)d_in[5];
    const float* b3 = (const float*)d_in[6];
    float* out = (float*)d_out;

    const int nrows   = in_sizes[0] / 2;          // B = 1048576
    const int nblocks = (nrows + TPB - 1) / TPB;  // 4096

    float*    t_part  = (float*)d_ws;
    int*      c_part  = (int*)((char*)d_ws + (size_t)nblocks * sizeof(float));
    unsigned* counter = (unsigned*)((char*)d_ws + (size_t)nblocks * 2 * sizeof(float));

    // ws is poisoned 0xAA before every timed launch -> zero the done-counter.
    hipMemsetAsync(counter, 0, sizeof(unsigned), stream);

    net_main<<<nblocks, TPB, 0, stream>>>(x, W1, b1, W2, b2, W3, b3,
                                          out, t_part, c_part, counter,
                                          nrows, 1.0 / (2.0 * (double)nrows));
}

// Round 11
// 150.181 us; speedup vs baseline: 1.2682x; 1.2682x over previous
//
#include <hip/hip_runtime.h>

#define TPB 256

typedef float f32x16 __attribute__((ext_vector_type(16)));

// Issue one 64B scalar load of W2 (row-half) into a pinned SGPR-16 block.
// Program order among volatile asms is preserved -> issue points are exact.
#define SLOAD16(dst, base, byteoff) \
    asm volatile("s_load_dwordx16 %0, %1, %2" : "=s"(dst) : "s"(base), "i"(byteoff))

// Drain SMEM. Tying the buffers as "+s" makes every consumer of them
// data-dependent on this asm (hipcc cannot hoist fmas above it, rule #18);
// tying the previous accumulators as "+v" pins the wait AFTER those fmas.
#define SWAIT2(b0, b1) \
    asm volatile("s_waitcnt lgkmcnt(0)" : "+s"(b0), "+s"(b1))
#define SWAIT4(b0, b1, v0, v1) \
    asm volatile("s_waitcnt lgkmcnt(0)" : "+s"(b0), "+s"(b1), "+v"(v0), "+v"(v1))

// ---------------------------------------------------------------------------
// partial_activation: identical math/order to all passing rounds (2/3/6/8/9) -
// do NOT reassociate: mask decisions are sign-sensitive. Constant indexing
// only (rule #20).
// ---------------------------------------------------------------------------
__device__ __forceinline__ void partial_act(float (&Y)[32], float& t_acc, int& s_cnt)
{
    int pos[16];
#pragma unroll
    for (int b = 0; b < 16; ++b)
        pos[b] = (Y[2 * b] > 0.0f ? 1 : 0) + (Y[2 * b + 1] > 0.0f ? 1 : 0);

    int minv = pos[0], maxv = pos[0];
    int minI = 0, maxI = 0;
    float ymin0 = Y[0], ymin1 = Y[1];
    float ymax0 = Y[0], ymax1 = Y[1];
#pragma unroll
    for (int b = 1; b < 16; ++b) {
        bool lt = pos[b] < minv;   // strict < keeps FIRST argmin (jnp.argmin)
        minv  = lt ? pos[b]       : minv;
        minI  = lt ? b            : minI;
        ymin0 = lt ? Y[2 * b]     : ymin0;
        ymin1 = lt ? Y[2 * b + 1] : ymin1;
        bool gt = pos[b] > maxv;   // strict > keeps FIRST argmax (jnp.argmax)
        maxv  = gt ? pos[b]       : maxv;
        maxI  = gt ? b            : maxI;
        ymax0 = gt ? Y[2 * b]     : ymax0;
        ymax1 = gt ? Y[2 * b + 1] : ymax1;
    }
    bool min_succ = (minv == 0);
    bool max_succ = (maxv == 2);

    float cmin = fmaxf(ymin0, 0.0f) + fmaxf(ymin1, 0.0f);
    float cmax = -(fminf(ymax0, 0.0f) + fminf(ymax1, 0.0f));
    t_acc += (min_succ ? 0.0f : cmin) + (max_succ ? 0.0f : cmax);
    s_cnt += (min_succ && max_succ) ? 1 : 0;

#pragma unroll
    for (int b = 0; b < 16; ++b) {
        bool ismax = max_succ && (b == maxI);
        bool ismin = min_succ && (b == minI);
        float mfac = ismax ? 2.0f : 1.0f;
        mfac = ismin ? 0.0f : mfac;
        Y[2 * b]     *= mfac;
        Y[2 * b + 1] *= mfac;
    }
}

// ---------------------------------------------------------------------------
// Round-11: R6 anchor (R=2, j-outer, SGPR weights = the only free broadcast)
// + EXPLICIT SOFTWARE PIPELINE of the W2 scalar loads.
//   Evidence: R2==R10 (130us) regardless of wave count, R6 87us @ busy 51% ->
//   all waves drain lgkmcnt(0) in lockstep each j (compiler issues row j's
//   s_load immediately before use). Pipeline: WAIT(A); issue B; fma(A) ~128cy;
//   WAIT(B); issue A'; fma(B) -> each load hides under one fma phase.
//   b2 is copied ONCE to VGPRs (bit-exact |0) so 64 SGPRs stay free for the
//   A/B weight buffers. fma chains scalar, ascending-k, init b2[j]:
//   bit-identical numerics to all passing rounds.
// ---------------------------------------------------------------------------
__global__ __launch_bounds__(TPB, 2) void net_main(
    const float* __restrict__ x,
    const float* __restrict__ W1, const float* __restrict__ b1,
    const float* __restrict__ W2, const float* __restrict__ b2,
    const float* __restrict__ W3, const float* __restrict__ b3,
    float* __restrict__ out,
    float* __restrict__ t_part, int* __restrict__ c_part,
    unsigned* __restrict__ counter,
    int half, int nrows, double inv_denom)
{
    const int tid = threadIdx.x;
    const int r0  = blockIdx.x * TPB + tid;

    float t_acc = 0.0f;
    int   s_cnt = 0;

    if (r0 < half) {
        const int r1 = r0 + half;
        const float2 xa = reinterpret_cast<const float2*>(x)[r0];
        const float2 xb = reinterpret_cast<const float2*>(x)[r1];

        // Issue W2 row 0 NOW -> its latency hides under layer 1 + both scans.
        f32x16 A0, A1, B0, B1;
        SLOAD16(A0, W2, 0);
        SLOAD16(A1, W2, 64);

        int zi;
        asm volatile("v_mov_b32 %0, 0" : "=v"(zi));   // opaque VGPR zero

        // ---- layer 1 for both rows (compiler: SGPR weights) ----
        float YA[32], YB[32];
#pragma unroll
        for (int j = 0; j < 32; ++j) {
            const float w0 = W1[2 * j], w1 = W1[2 * j + 1], bb = b1[j];
            YA[j] = fmaf(xa.y, w1, fmaf(xa.x, w0, bb));
            YB[j] = fmaf(xb.y, w1, fmaf(xb.x, w0, bb));
        }

        partial_act(YA, t_acc, s_cnt);
        partial_act(YB, t_acc, s_cnt);

        // ---- b2 -> VGPRs, bit-exact (frees SGPRs for the pipeline) ----
        float b2r[32];
#pragma unroll
        for (int k = 0; k < 32; ++k)
            b2r[k] = __int_as_float(__float_as_int(b2[k]) | zi);

        // ---- layer 2: software-pipelined j-outer loop ----
        float ZA[32], ZB[32];
#pragma unroll
        for (int jj = 0; jj < 16; ++jj) {
            const int j0 = 2 * jj, j1 = 2 * jj + 1;

            SWAIT2(A0, A1);                       // A flew during prev phase
            SLOAD16(B0, W2, j1 * 128);            // issue next row
            SLOAD16(B1, W2, j1 * 128 + 64);

            float a0 = b2r[j0];
            float a1 = b2r[j0];
#pragma unroll
            for (int k = 0; k < 16; ++k) {        // ascending-k chain (exact)
                a0 = fmaf(YA[k], A0[k], a0);
                a1 = fmaf(YB[k], A0[k], a1);
            }
#pragma unroll
            for (int k = 0; k < 16; ++k) {
                a0 = fmaf(YA[16 + k], A1[k], a0);
                a1 = fmaf(YB[16 + k], A1[k], a1);
            }
            ZA[j0] = a0;
            ZB[j0] = a1;

            SWAIT4(B0, B1, a0, a1);               // after fma-A; B has flown
            if (jj < 15) {
                SLOAD16(A0, W2, (j0 + 2) * 128);  // issue row j0+2
                SLOAD16(A1, W2, (j0 + 2) * 128 + 64);
            }

            float c0 = b2r[j1];
            float c1 = b2r[j1];
#pragma unroll
            for (int k = 0; k < 16; ++k) {
                c0 = fmaf(YA[k], B0[k], c0);
                c1 = fmaf(YB[k], B0[k], c1);
            }
#pragma unroll
            for (int k = 0; k < 16; ++k) {
                c0 = fmaf(YA[16 + k], B1[k], c0);
                c1 = fmaf(YB[16 + k], B1[k], c1);
            }
            ZA[j1] = c0;
            ZB[j1] = c1;
        }

        partial_act(ZA, t_acc, s_cnt);
        partial_act(ZB, t_acc, s_cnt);

        // ---- layer 3 + softmax, both rows (same order as passing rounds) ----
        {
            float z0 = b3[0], z1 = b3[1];
            float y0 = b3[0], y1 = b3[1];
#pragma unroll
            for (int k = 0; k < 32; ++k) {
                const float wa = W3[k], wb = W3[32 + k];
                z0 = fmaf(ZA[k], wa, z0);
                z1 = fmaf(ZA[k], wb, z1);
                y0 = fmaf(ZB[k], wa, y0);
                y1 = fmaf(ZB[k], wb, y1);
            }
            float m0  = fmaxf(z0, z1);
            float e00 = __expf(z0 - m0);
            float e01 = __expf(z1 - m0);
            float i0  = 1.0f / (e00 + e01);
            float2 oa; oa.x = e00 * i0; oa.y = e01 * i0;
            reinterpret_cast<float2*>(out)[r0] = oa;

            float m1  = fmaxf(y0, y1);
            float e10 = __expf(y0 - m1);
            float e11 = __expf(y1 - m1);
            float i1  = 1.0f / (e10 + e11);
            float2 ob; ob.x = e10 * i1; ob.y = e11 * i1;
            reinterpret_cast<float2*>(out)[r1] = ob;
        }
    }

    // ---- block reduction: wave shuffle -> LDS -> per-block partial ----
#pragma unroll
    for (int off = 32; off; off >>= 1) {
        t_acc += __shfl_down(t_acc, off);
        s_cnt += __shfl_down(s_cnt, off);
    }
    __shared__ float ts[TPB / 64];
    __shared__ int   cs[TPB / 64];
    __shared__ bool  amLast;
    const int wid  = tid >> 6;
    const int lane = tid & 63;
    if (lane == 0) { ts[wid] = t_acc; cs[wid] = s_cnt; }
    __syncthreads();
    if (tid == 0) {
        float tt = ts[0];
        int   cc = cs[0];
#pragma unroll
        for (int w = 1; w < TPB / 64; ++w) { tt += ts[w]; cc += cs[w]; }
        t_part[blockIdx.x] = tt;
        c_part[blockIdx.x] = cc;
        __threadfence();                        // partials visible device-wide
        unsigned old = atomicAdd(counter, 1u);  // device-scope by default
        amLast = (old == gridDim.x - 1);
    }
    __syncthreads();

    // ---- last block reduces all partials (fixed order -> deterministic) ----
    if (amLast) {
        __threadfence();
        double t = 0.0;
        int    c = 0;
        const int nparts = gridDim.x;
        for (int i = tid; i < nparts; i += TPB) {
            t += (double)t_part[i];
            c += c_part[i];
        }
#pragma unroll
        for (int off = 32; off; off >>= 1) {
            t += __shfl_down(t, off);
            c += __shfl_down(c, off);
        }
        __shared__ double td[TPB / 64];
        __shared__ int    cd[TPB / 64];
        if (lane == 0) { td[wid] = t; cd[wid] = c; }
        __syncthreads();
        if (tid == 0) {
            double tt = 0.0;
            int    cc = 0;
#pragma unroll
            for (int w = 0; w < TPB / 64; ++w) { tt += td[w]; cc += cd[w]; }
            float* scal = out + (size_t)nrows * 2;
            scal[0] = (float)((double)cc * inv_denom); // succ = cnt / (2B)
            scal[1] = (float)tt;                       // train = t1 + t2
        }
    }
}

extern "C" void kernel_launch(void* const* d_in, const int* in_sizes, int n_in,
                              void* d_out, int out_size, void* d_ws, size_t ws_size,
                              hipStream_t stream)
{
    const float* x  = (const float*)d_in[0];
    const float* W1 = (const float*)d_in[1];
    const float* b1 = (const float*)d_in[2];
    const float* W2 = (const float*)d_in[3];
    const float* b2 = (const float*)d_in[4];
    const float* W3 = (const float*)d_in[5];
    const float* b3 = (const float*)d_in[6];
    float* out = (float*)d_out;

    const int nrows   = in_sizes[0] / 2;          // B = 1048576
    const int half    = nrows / 2;                // 2 rows per thread
    const int nblocks = (half + TPB - 1) / TPB;   // 2048

    float*    t_part  = (float*)d_ws;
    int*      c_part  = (int*)((char*)d_ws + (size_t)nblocks * sizeof(float));
    unsigned* counter = (unsigned*)((char*)d_ws + (size_t)nblocks * 2 * sizeof(float));

    // ws is poisoned 0xAA before every timed launch -> zero the done-counter.
    hipMemsetAsync(counter, 0, sizeof(unsigned), stream);

    net_main<<<nblocks, TPB, 0, stream>>>(x, W1, b1, W2, b2, W3, b3,
                                          out, t_part, c_part, counter,
                                          half, nrows, 1.0 / (2.0 * (double)nrows));
}